// Round 1
// baseline (6503.545 us; speedup 1.0000x reference)
//
#include <hip/hip_runtime.h>
#include <cstdint>
#include <cstddef>

// Problem constants
#define BB   64     // batch
#define TT   512    // time steps
#define HH   256    // hidden
#define G4   1024   // 4*H
#define NL   8      // layers
#define NW   32     // workgroups per layer (hidden-unit slices)
#define HPW  8      // hidden units per WG
#define NR   32     // gate rows per WG (4 gates * HPW)

typedef _Float16 half8 __attribute__((ext_vector_type(8)));
typedef float   floatx4 __attribute__((ext_vector_type(4)));

__device__ __forceinline__ float sigm(float v)   { return 1.0f / (1.0f + __expf(-v)); }
__device__ __forceinline__ float tanh_f(float v) { return 1.0f - 2.0f / (__expf(2.0f * v) + 1.0f); }

// hseq layout per layer: [t][kblk=H/8=32][b=64][8] fp16   (MFMA A-fragment friendly)
#define TSTRIDE ((size_t)32 * BB * 8)         // elements per t  = 16384
#define LSTRIDE ((size_t)TT * TSTRIDE)        // elements per layer = 8,388,608 (16 MB)

// ---------------------------------------------------------------------------
// xg0 table: table[v][n] = sum_e emb[v][e] * Wih0[n][e]   (biases NOT included)
__global__ void build_xg0(const float* __restrict__ emb, const float* __restrict__ Wih0,
                          float* __restrict__ table) {
  int i = blockIdx.x * 256 + threadIdx.x;
  if (i >= 23 * G4) return;
  int v = i >> 10, n = i & (G4 - 1);
  float a = 0.f;
#pragma unroll
  for (int e = 0; e < 16; ++e) a += emb[v * 16 + e] * Wih0[n * 16 + e];
  table[i] = a;
}

// ---------------------------------------------------------------------------
// Persistent pipelined LSTM. grid = 256 blocks (NL layers x NW slices), 256 thr.
// block b: layer = b & 7 (XCD-affinity heuristic), slice w = b >> 3.
__global__ __launch_bounds__(256, 1) void lstm_pipeline(
    const int*   __restrict__ x,         // [B][T]
    const float* __restrict__ Wih_rest,  // [7][1024][256]
    const float* __restrict__ Whh,       // [8][1024][256]
    const float* __restrict__ bih,       // [8][1024]
    const float* __restrict__ bhh,       // [8][1024]
    const float* __restrict__ xg0t,      // [23][1024]
    _Float16* __restrict__ hseq,         // NL * LSTRIDE fp16
    int* __restrict__ flags)             // [NL][TT]
{
  const int l   = blockIdx.x & 7;
  const int w   = blockIdx.x >> 3;
  const int tid = threadIdx.x;
  const int lane = tid & 63;
  const int p    = tid >> 6;        // wave index = M-tile index (batch/16)
  const int bb   = tid & 63;        // this thread's batch for the cell phase

  // LDS: weights 32KB + gates 8.4KB + h-stage 1KB + bias + xg0 slice  (~45KB)
  __shared__ __align__(16) _Float16 wlds[64 * NR * 8]; // [kc 0..63][n 0..31][8]
  __shared__ float  glds[BB * 33];                     // padded: bank-conflict-free
  __shared__ __align__(16) _Float16 hl[BB * 8];
  __shared__ float  blds[NR];
  __shared__ float  tlds[23 * NR];

  // ---- one-time init: gather this WG's 32 gate rows into LDS as fp16 ----
  // local row n: gate g = n>>3, unit jl = n&7 -> global gate row gr = g*256 + w*8 + jl
  for (int idx = tid; idx < 64 * NR; idx += 256) {
    int kc = idx >> 5;          // 0..63 : k-chunk of 8 (0..31 input half, 32..63 recurrent)
    int n  = idx & 31;
    int g = n >> 3, jl = n & 7;
    int gr = g * 256 + w * HPW + jl;
    float v[8];
    if (kc < 32) {
      if (l == 0) { for (int j = 0; j < 8; ++j) v[j] = 0.f; }
      else {
        const float* src = Wih_rest + ((size_t)(l - 1) * G4 + gr) * HH + kc * 8;
        for (int j = 0; j < 8; ++j) v[j] = src[j];
      }
    } else {
      const float* src = Whh + ((size_t)l * G4 + gr) * HH + (kc - 32) * 8;
      for (int j = 0; j < 8; ++j) v[j] = src[j];
    }
    _Float16* dst = wlds + (size_t)idx * 8;
    for (int j = 0; j < 8; ++j) dst[j] = (_Float16)v[j];
  }
  if (tid < NR) {
    int g = tid >> 3, jl = tid & 7;
    int gr = g * 256 + w * HPW + jl;
    blds[tid] = bih[l * G4 + gr] + bhh[l * G4 + gr];
  }
  if (l == 0) {
    for (int idx = tid; idx < 23 * NR; idx += 256) {
      int v = idx >> 5, n = idx & 31;
      int g = n >> 3, jl = n & 7;
      tlds[idx] = xg0t[v * G4 + g * 256 + w * HPW + jl];
    }
  }
  __syncthreads();

  // persistent cell state: thread owns (bb, j=2p) and (bb, j=2p+1)
  float c0 = 0.f, c1 = 0.f;

  const int arow = p * 16 + (lane & 15);  // A-fragment batch row
  const int kq   = lane >> 4;             // quarter-wave -> k chunk within tile
  const int n0   = lane & 15;             // B-fragment col (tile 0)
  const int n1   = 16 + n0;               // B-fragment col (tile 1)

  const _Float16* hin  = hseq + (size_t)(l > 0 ? l - 1 : 0) * LSTRIDE;
  _Float16*       hrec = hseq + (size_t)l * LSTRIDE;
  int* flg_in  = flags + (l > 0 ? (l - 1) * TT : 0);
  int* flg_own = flags + l * TT;

  for (int t = 0; t < TT; ++t) {
    // ---- wait on producers (relaxed poll, then one acquire fence) ----
    if (tid == 0) {
      if (l > 0)
        while (__hip_atomic_load(flg_in + t, __ATOMIC_RELAXED, __HIP_MEMORY_SCOPE_AGENT) < NW)
          __builtin_amdgcn_s_sleep(1);
      if (t > 0)
        while (__hip_atomic_load(flg_own + (t - 1), __ATOMIC_RELAXED, __HIP_MEMORY_SCOPE_AGENT) < NW)
          __builtin_amdgcn_s_sleep(1);
      __threadfence();   // acquire: invalidate caches so fresh h is visible
    }
    __syncthreads();

    floatx4 acc0 = {0.f, 0.f, 0.f, 0.f};
    floatx4 acc1 = {0.f, 0.f, 0.f, 0.f};

    // ---- input half: k in [0,256) = h_{l-1}[t]  (skipped for layer 0) ----
    if (l > 0) {
      const _Float16* ain = hin + (size_t)t * TSTRIDE;
#pragma unroll
      for (int kt = 0; kt < 8; ++kt) {
        int kc = kt * 4 + kq;
        half8 a  = *(const half8*)(ain + ((size_t)(kc * 64 + arow) << 3));
        half8 w0 = *(const half8*)(wlds + ((kc * 32 + n0) << 3));
        half8 w1 = *(const half8*)(wlds + ((kc * 32 + n1) << 3));
        acc0 = __builtin_amdgcn_mfma_f32_16x16x32_f16(a, w0, acc0, 0, 0, 0);
        acc1 = __builtin_amdgcn_mfma_f32_16x16x32_f16(a, w1, acc1, 0, 0, 0);
      }
    }
    // ---- recurrent half: k in [256,512) = h_l[t-1]  (skipped at t==0) ----
    if (t > 0) {
      const _Float16* ain = hrec + (size_t)(t - 1) * TSTRIDE;
#pragma unroll
      for (int kt = 0; kt < 8; ++kt) {
        int kc = kt * 4 + kq;
        half8 a  = *(const half8*)(ain + ((size_t)(kc * 64 + arow) << 3));
        half8 w0 = *(const half8*)(wlds + (((32 + kc) * 32 + n0) << 3));
        half8 w1 = *(const half8*)(wlds + (((32 + kc) * 32 + n1) << 3));
        acc0 = __builtin_amdgcn_mfma_f32_16x16x32_f16(a, w0, acc0, 0, 0, 0);
        acc1 = __builtin_amdgcn_mfma_f32_16x16x32_f16(a, w1, acc1, 0, 0, 0);
      }
    }

    // ---- write gate pre-activations to LDS (C layout: col=lane&15, row=quad*4+reg) ----
    {
      int rbase = p * 16 + kq * 4;
#pragma unroll
      for (int r = 0; r < 4; ++r) {
        glds[(rbase + r) * 33 + n0]      = acc0[r];
        glds[(rbase + r) * 33 + 16 + n0] = acc1[r];
      }
    }
    __syncthreads();

    // ---- cell update: thread handles (bb, 2p) and (bb, 2p+1) ----
    {
      int xv = 0;
      if (l == 0) xv = x[bb * TT + t];
      float h0, h1;
#pragma unroll
      for (int q = 0; q < 2; ++q) {
        int j = 2 * p + q;
        float gi = glds[bb * 33 + j]      + blds[j];
        float gf = glds[bb * 33 + 8 + j]  + blds[8 + j];
        float gg = glds[bb * 33 + 16 + j] + blds[16 + j];
        float go = glds[bb * 33 + 24 + j] + blds[24 + j];
        if (l == 0) {
          const float* tb = tlds + xv * NR;
          gi += tb[j]; gf += tb[8 + j]; gg += tb[16 + j]; go += tb[24 + j];
        }
        float iv = sigm(gi), fv = sigm(gf), gv = tanh_f(gg), ov = sigm(go);
        float cv = (q == 0) ? c0 : c1;
        cv = fv * cv + iv * gv;
        float hv = ov * tanh_f(cv);
        if (q == 0) { c0 = cv; h0 = hv; } else { c1 = cv; h1 = hv; }
      }
      hl[bb * 8 + 2 * p]     = (_Float16)h0;
      hl[bb * 8 + 2 * p + 1] = (_Float16)h1;
    }
    __syncthreads();

    // ---- publish h slice: hseq[l][t][kblk=w][b][0..8)  (64 x 16B coalesced) ----
    if (tid < 64) {
      half8 hv = *(const half8*)(hl + tid * 8);
      *(half8*)(hrec + (size_t)t * TSTRIDE + ((size_t)w * 64 + tid) * 8) = hv;
    }
    __syncthreads();   // drains vmcnt for all publishing waves

    if (tid == 0) {
      __threadfence();  // release: flush L2 so other XCDs see h
      __hip_atomic_fetch_add(flg_own + t, 1, __ATOMIC_RELAXED, __HIP_MEMORY_SCOPE_AGENT);
    }
  }
}

// ---------------------------------------------------------------------------
// Final projection: out[b][t][v] = h7[b][t][:] . fc_w[v][:] + fc_b[v]
__global__ __launch_bounds__(256) void fc_kernel(
    const _Float16* __restrict__ hseq7,  // [T][32][64][8] fp16
    const float* __restrict__ fcw,       // [23][256]
    const float* __restrict__ fcb,       // [23]
    float* __restrict__ out)             // [64][512][23]
{
  const int t = blockIdx.x;
  const int tid = threadIdx.x;
  __shared__ __align__(16) _Float16 hbuf[32 * 64 * 8];
  __shared__ float wbuf[23 * 256];
  __shared__ float bbuf[24];

  const _Float16* src = hseq7 + (size_t)t * TSTRIDE;
  for (int i = tid; i < 32 * 64; i += 256)
    ((half8*)hbuf)[i] = ((const half8*)src)[i];
  for (int i = tid; i < 23 * 256; i += 256) wbuf[i] = fcw[i];
  if (tid < 23) bbuf[tid] = fcb[tid];
  __syncthreads();

  for (int o = tid; o < 64 * 23; o += 256) {
    int b = o / 23, v = o - b * 23;
    float acc = bbuf[v];
#pragma unroll 4
    for (int kc = 0; kc < 32; ++kc) {
      half8 hv = *(const half8*)(hbuf + ((kc * 64 + b) << 3));
      const float* wr = wbuf + v * 256 + kc * 8;
#pragma unroll
      for (int j = 0; j < 8; ++j) acc += (float)hv[j] * wr[j];
    }
    out[((size_t)b * TT + t) * 23 + v] = acc;
  }
}

// ---------------------------------------------------------------------------
extern "C" void kernel_launch(void* const* d_in, const int* in_sizes, int n_in,
                              void* d_out, int out_size, void* d_ws, size_t ws_size,
                              hipStream_t stream) {
  const int*   x        = (const int*)d_in[0];
  const float* emb      = (const float*)d_in[1];
  const float* Wih0     = (const float*)d_in[2];
  const float* Wih_rest = (const float*)d_in[3];
  const float* Whh      = (const float*)d_in[4];
  const float* bihp     = (const float*)d_in[5];
  const float* bhhp     = (const float*)d_in[6];
  const float* fcw      = (const float*)d_in[7];
  const float* fcb      = (const float*)d_in[8];
  float* out = (float*)d_out;

  char* ws = (char*)d_ws;
  // ws layout: flags 16KB | xg0 table 94KB | (align 128KB) | hseq 128MB
  int*      flags = (int*)ws;                          // NL*TT*4 = 16384 B
  float*    table = (float*)(ws + 16384);              // 23*1024*4 = 94208 B
  _Float16* hseq  = (_Float16*)(ws + 131072);          // 8 * 16 MB

  hipMemsetAsync(flags, 0, NL * TT * sizeof(int), stream);
  build_xg0<<<(23 * G4 + 255) / 256, 256, 0, stream>>>(emb, Wih0, table);
  lstm_pipeline<<<NL * NW, 256, 0, stream>>>(x, Wih_rest, Whh, bihp, bhhp, table, hseq, flags);
  fc_kernel<<<TT, 256, 0, stream>>>(hseq + (size_t)7 * LSTRIDE, fcw, fcb, out);
}

// Round 2
// 1926.710 us; speedup vs baseline: 3.3755x; 3.3755x over previous
//
#include <hip/hip_runtime.h>
#include <cstdint>
#include <cstddef>

// Problem constants
#define BB   64     // batch
#define TT   512    // time steps
#define HH   256    // hidden
#define G4   1024   // 4*H
#define NL   8      // layers
#define NW   32     // workgroups per layer (hidden-unit slices)
#define HPW  8      // hidden units per WG
#define NR   32     // gate rows per WG (4 gates * HPW)

typedef _Float16 half8 __attribute__((ext_vector_type(8)));
typedef float   floatx4 __attribute__((ext_vector_type(4)));

__device__ __forceinline__ float sigm(float v)   { return 1.0f / (1.0f + __expf(-v)); }
__device__ __forceinline__ float tanh_f(float v) { return 1.0f - 2.0f / (__expf(2.0f * v) + 1.0f); }

// Coherent (cross-XCD) 16B load/store: sc0 sc1 bypass L1/L2, served at IF$.
// This replaces heavyweight __threadfence (buffer_wbl2/buffer_inv) sync.
__device__ __forceinline__ void gload8(half8& d, const _Float16* p) {
  asm volatile("global_load_dwordx4 %0, %1, off sc0 sc1"
               : "=v"(d) : "v"(p) : "memory");
}
__device__ __forceinline__ void gstore8(const _Float16* p, half8 d) {
  asm volatile("global_store_dwordx4 %0, %1, off sc0 sc1"
               :: "v"(p), "v"(d) : "memory");
}
__device__ __forceinline__ void wait_vm0() {
  asm volatile("s_waitcnt vmcnt(0)" ::: "memory");
}

// hseq layout per layer: [t][kblk=H/8=32][b=64][8] fp16   (MFMA A-fragment friendly)
#define TSTRIDE ((size_t)32 * BB * 8)         // elements per t  = 16384
#define LSTRIDE ((size_t)TT * TSTRIDE)        // elements per layer = 8,388,608 (16 MB)

// ---------------------------------------------------------------------------
// xg0 table: table[v][n] = sum_e emb[v][e] * Wih0[n][e]   (biases NOT included)
__global__ void build_xg0(const float* __restrict__ emb, const float* __restrict__ Wih0,
                          float* __restrict__ table) {
  int i = blockIdx.x * 256 + threadIdx.x;
  if (i >= 23 * G4) return;
  int v = i >> 10, n = i & (G4 - 1);
  float a = 0.f;
#pragma unroll
  for (int e = 0; e < 16; ++e) a += emb[v * 16 + e] * Wih0[n * 16 + e];
  table[i] = a;
}

// ---------------------------------------------------------------------------
// Persistent pipelined LSTM. grid = 256 blocks (NL layers x NW slices), 256 thr.
__global__ __launch_bounds__(256, 1) void lstm_pipeline(
    const int*   __restrict__ x,         // [B][T]
    const float* __restrict__ Wih_rest,  // [7][1024][256]
    const float* __restrict__ Whh,       // [8][1024][256]
    const float* __restrict__ bih,       // [8][1024]
    const float* __restrict__ bhh,       // [8][1024]
    const float* __restrict__ xg0t,      // [23][1024]
    _Float16* __restrict__ hseq,         // NL * LSTRIDE fp16
    int* __restrict__ flags)             // [NL][TT]
{
  const int l   = blockIdx.x & 7;
  const int w   = blockIdx.x >> 3;
  const int tid = threadIdx.x;
  const int lane = tid & 63;
  const int p    = tid >> 6;        // wave index = M-tile index (batch/16)
  const int bb   = tid & 63;        // this thread's batch for the cell phase

  __shared__ __align__(16) _Float16 wlds[64 * NR * 8]; // [kc 0..63][n 0..31][8]
  __shared__ float  glds[BB * 33];                     // padded
  __shared__ __align__(16) _Float16 hl[BB * 8];
  __shared__ float  blds[NR];
  __shared__ float  tlds[23 * NR];

  // ---- one-time init: gather this WG's 32 gate rows into LDS as fp16 ----
  for (int idx = tid; idx < 64 * NR; idx += 256) {
    int kc = idx >> 5;          // 0..63 : k-chunk of 8 (0..31 input half, 32..63 recurrent)
    int n  = idx & 31;
    int g = n >> 3, jl = n & 7;
    int gr = g * 256 + w * HPW + jl;
    float v[8];
    if (kc < 32) {
      if (l == 0) { for (int j = 0; j < 8; ++j) v[j] = 0.f; }
      else {
        const float* src = Wih_rest + ((size_t)(l - 1) * G4 + gr) * HH + kc * 8;
        for (int j = 0; j < 8; ++j) v[j] = src[j];
      }
    } else {
      const float* src = Whh + ((size_t)l * G4 + gr) * HH + (kc - 32) * 8;
      for (int j = 0; j < 8; ++j) v[j] = src[j];
    }
    _Float16* dst = wlds + (size_t)idx * 8;
    for (int j = 0; j < 8; ++j) dst[j] = (_Float16)v[j];
  }
  if (tid < NR) {
    int g = tid >> 3, jl = tid & 7;
    int gr = g * 256 + w * HPW + jl;
    blds[tid] = bih[l * G4 + gr] + bhh[l * G4 + gr];
  }
  if (l == 0) {
    for (int idx = tid; idx < 23 * NR; idx += 256) {
      int v = idx >> 5, n = idx & 31;
      int g = n >> 3, jl = n & 7;
      tlds[idx] = xg0t[v * G4 + g * 256 + w * HPW + jl];
    }
  }
  __syncthreads();

  float c0 = 0.f, c1 = 0.f;

  const int arow = p * 16 + (lane & 15);  // A-fragment batch row
  const int kq   = lane >> 4;             // quarter-wave -> k chunk within tile
  const int n0   = lane & 15;             // B-fragment col (tile 0)
  const int n1   = 16 + n0;               // B-fragment col (tile 1)

  const _Float16* hin  = hseq + (size_t)(l > 0 ? l - 1 : 0) * LSTRIDE;
  _Float16*       hrec = hseq + (size_t)l * LSTRIDE;
  int* flg_in  = flags + (l > 0 ? (l - 1) * TT : 0);
  int* flg_own = flags + l * TT;

  for (int t = 0; t < TT; ++t) {
    floatx4 acc0 = {0.f, 0.f, 0.f, 0.f};
    floatx4 acc1 = {0.f, 0.f, 0.f, 0.f};

    // ========== Phase A: input half (k in [0,256) = h_{l-1}[t]) ==========
    // Waits only on the layer below; in steady state this flag is already set,
    // keeping input-half load latency OFF the recurrence-critical chain.
    if (tid == 0 && l > 0) {
      while (__hip_atomic_load(flg_in + t, __ATOMIC_RELAXED, __HIP_MEMORY_SCOPE_AGENT) < NW)
        __builtin_amdgcn_s_sleep(1);
    }
    __syncthreads();   // barrier 1

    if (l > 0) {
      const _Float16* ain = hin + (size_t)t * TSTRIDE;
      half8 a[8];
#pragma unroll
      for (int kt = 0; kt < 8; ++kt) {
        int kc = kt * 4 + kq;
        gload8(a[kt], ain + ((size_t)(kc * 64 + arow) << 3));
      }
      wait_vm0();
#pragma unroll
      for (int kt = 0; kt < 8; ++kt) {
        int kc = kt * 4 + kq;
        half8 w0 = *(const half8*)(wlds + ((kc * 32 + n0) << 3));
        half8 w1 = *(const half8*)(wlds + ((kc * 32 + n1) << 3));
        acc0 = __builtin_amdgcn_mfma_f32_16x16x32_f16(a[kt], w0, acc0, 0, 0, 0);
        acc1 = __builtin_amdgcn_mfma_f32_16x16x32_f16(a[kt], w1, acc1, 0, 0, 0);
      }
    }

    // ========== Phase B: recurrent half (k in [256,512) = h_l[t-1]) ==========
    if (tid == 0 && t > 0) {
      while (__hip_atomic_load(flg_own + (t - 1), __ATOMIC_RELAXED, __HIP_MEMORY_SCOPE_AGENT) < NW)
        __builtin_amdgcn_s_sleep(1);
    }
    __syncthreads();   // barrier 2

    if (t > 0) {
      const _Float16* ain = hrec + (size_t)(t - 1) * TSTRIDE;
      half8 a[8];
#pragma unroll
      for (int kt = 0; kt < 8; ++kt) {
        int kc = kt * 4 + kq;
        gload8(a[kt], ain + ((size_t)(kc * 64 + arow) << 3));
      }
      wait_vm0();
#pragma unroll
      for (int kt = 0; kt < 8; ++kt) {
        int kc = kt * 4 + kq;
        half8 w0 = *(const half8*)(wlds + (((32 + kc) * 32 + n0) << 3));
        half8 w1 = *(const half8*)(wlds + (((32 + kc) * 32 + n1) << 3));
        acc0 = __builtin_amdgcn_mfma_f32_16x16x32_f16(a[kt], w0, acc0, 0, 0, 0);
        acc1 = __builtin_amdgcn_mfma_f32_16x16x32_f16(a[kt], w1, acc1, 0, 0, 0);
      }
    }

    // ---- write gate pre-activations to LDS (C layout: col=lane&15, row=quad*4+reg) ----
    {
      int rbase = p * 16 + kq * 4;
#pragma unroll
      for (int r = 0; r < 4; ++r) {
        glds[(rbase + r) * 33 + n0]      = acc0[r];
        glds[(rbase + r) * 33 + 16 + n0] = acc1[r];
      }
    }
    __syncthreads();   // barrier 3

    // ---- cell update: thread handles (bb, 2p) and (bb, 2p+1) ----
    {
      int xv = 0;
      if (l == 0) xv = x[bb * TT + t];
      float h0, h1;
#pragma unroll
      for (int q = 0; q < 2; ++q) {
        int j = 2 * p + q;
        float gi = glds[bb * 33 + j]      + blds[j];
        float gf = glds[bb * 33 + 8 + j]  + blds[8 + j];
        float gg = glds[bb * 33 + 16 + j] + blds[16 + j];
        float go = glds[bb * 33 + 24 + j] + blds[24 + j];
        if (l == 0) {
          const float* tb = tlds + xv * NR;
          gi += tb[j]; gf += tb[8 + j]; gg += tb[16 + j]; go += tb[24 + j];
        }
        float iv = sigm(gi), fv = sigm(gf), gv = tanh_f(gg), ov = sigm(go);
        float cv = (q == 0) ? c0 : c1;
        cv = fv * cv + iv * gv;
        float hv = ov * tanh_f(cv);
        if (q == 0) { c0 = cv; h0 = hv; } else { c1 = cv; h1 = hv; }
      }
      hl[bb * 8 + 2 * p]     = (_Float16)h0;
      hl[bb * 8 + 2 * p + 1] = (_Float16)h1;
    }
    __syncthreads();   // barrier 4

    // ---- publish h slice via coherent stores (wave 0 only: 64 x 16B) ----
    if (tid < 64) {
      half8 hv = *(const half8*)(hl + tid * 8);
      gstore8(hrec + (size_t)t * TSTRIDE + ((size_t)w * 64 + tid) * 8, hv);
      wait_vm0();   // stores reached the coherence point (IF$) -> release
      if (tid == 0)
        __hip_atomic_fetch_add(flg_own + t, 1, __ATOMIC_RELAXED, __HIP_MEMORY_SCOPE_AGENT);
    }
    // next iteration's barrier 1 closes the step
  }
}

// ---------------------------------------------------------------------------
// Final projection: out[b][t][v] = h7[b][t][:] . fc_w[v][:] + fc_b[v]
__global__ __launch_bounds__(256) void fc_kernel(
    const _Float16* __restrict__ hseq7,  // [T][32][64][8] fp16
    const float* __restrict__ fcw,       // [23][256]
    const float* __restrict__ fcb,       // [23]
    float* __restrict__ out)             // [64][512][23]
{
  const int t = blockIdx.x;
  const int tid = threadIdx.x;
  __shared__ __align__(16) _Float16 hbuf[32 * 64 * 8];
  __shared__ float wbuf[23 * 256];
  __shared__ float bbuf[24];

  const _Float16* src = hseq7 + (size_t)t * TSTRIDE;
  for (int i = tid; i < 32 * 64; i += 256)
    ((half8*)hbuf)[i] = ((const half8*)src)[i];
  for (int i = tid; i < 23 * 256; i += 256) wbuf[i] = fcw[i];
  if (tid < 23) bbuf[tid] = fcb[tid];
  __syncthreads();

  for (int o = tid; o < 64 * 23; o += 256) {
    int b = o / 23, v = o - b * 23;
    float acc = bbuf[v];
#pragma unroll 4
    for (int kc = 0; kc < 32; ++kc) {
      half8 hv = *(const half8*)(hbuf + ((kc * 64 + b) << 3));
      const float* wr = wbuf + v * 256 + kc * 8;
#pragma unroll
      for (int j = 0; j < 8; ++j) acc += (float)hv[j] * wr[j];
    }
    out[((size_t)b * TT + t) * 23 + v] = acc;
  }
}

// ---------------------------------------------------------------------------
extern "C" void kernel_launch(void* const* d_in, const int* in_sizes, int n_in,
                              void* d_out, int out_size, void* d_ws, size_t ws_size,
                              hipStream_t stream) {
  const int*   x        = (const int*)d_in[0];
  const float* emb      = (const float*)d_in[1];
  const float* Wih0     = (const float*)d_in[2];
  const float* Wih_rest = (const float*)d_in[3];
  const float* Whh      = (const float*)d_in[4];
  const float* bihp     = (const float*)d_in[5];
  const float* bhhp     = (const float*)d_in[6];
  const float* fcw      = (const float*)d_in[7];
  const float* fcb      = (const float*)d_in[8];
  float* out = (float*)d_out;

  char* ws = (char*)d_ws;
  // ws layout: flags 16KB | xg0 table 94KB | (align 128KB) | hseq 128MB
  int*      flags = (int*)ws;                          // NL*TT*4 = 16384 B
  float*    table = (float*)(ws + 16384);              // 23*1024*4 = 94208 B
  _Float16* hseq  = (_Float16*)(ws + 131072);          // 8 * 16 MB

  hipMemsetAsync(flags, 0, NL * TT * sizeof(int), stream);
  build_xg0<<<(23 * G4 + 255) / 256, 256, 0, stream>>>(emb, Wih0, table);
  lstm_pipeline<<<NL * NW, 256, 0, stream>>>(x, Wih_rest, Whh, bihp, bhhp, table, hseq, flags);
  fc_kernel<<<TT, 256, 0, stream>>>(hseq + (size_t)7 * LSTRIDE, fcw, fcb, out);
}